// Round 3
// baseline (299.631 us; speedup 1.0000x reference)
//
#include <hip/hip_runtime.h>

// DepthAugmentation: fused noise-upsample + dropout + random-replace (kernel 1),
// then per-batch stick rectangle fill (kernel 2, needs post-aug depth at (y,x)).
//
// Shapes: depth/dropout_u/random_u/random_vals: (64,1,480,640) f32
//         noise_lo: (64,1,120,160) f32; per-batch scalars/ints: (64,)

constexpr int Bc  = 64;
constexpr int Hc  = 480;
constexpr int Wc  = 640;
constexpr int HLO = 120;
constexpr int WLO = 160;
constexpr int W4  = Wc / 4;          // 160 float4 groups per row
constexpr int HW  = Hc * Wc;         // 307200

#define NOISE_SIGMA 0.005f
#define P_DROPOUT   0.003125f
#define P_RANDOM    0.003125f
#define STICK_THRESH 76.8f           // P_STICK * H * W = 0.00025 * 307200

__global__ __launch_bounds__(256) void aug_main_kernel(
    const float* __restrict__ depth,
    const float* __restrict__ noise_lo,
    const float* __restrict__ dropout_u,
    const float* __restrict__ random_u,
    const float* __restrict__ random_vals,
    float* __restrict__ out)
{
    const int b = blockIdx.y;
    const int t = blockIdx.x * 256 + threadIdx.x;   // [0, 76800) exactly: 300 blocks * 256
    const int y = t / W4;
    const int c = t - y * W4;                       // float4 group index == lo-column index

    // ---- vertical bilinear setup (half-pixel: in_y = y*0.25 - 0.375) ----
    // y = 4k+r: r=0 -> y0=k-1, fy=.625 ; r=1 -> y0=k-1, fy=.875
    //           r=2 -> y0=k,   fy=.125 ; r=3 -> y0=k,   fy=.375
    const int r = y & 3, k = y >> 2;
    const int y0 = (r < 2) ? (k - 1) : k;
    const float fy = (r == 0) ? 0.625f : (r == 1) ? 0.875f : (r == 2) ? 0.125f : 0.375f;
    const float gy = 1.0f - fy;
    const int ya = max(y0, 0);
    const int yb = min(y0 + 1, HLO - 1);

    // ---- gather 6 lo values (heavily L1/L2-cached; ~4.9MB total footprint) ----
    const float* lo = noise_lo + (size_t)b * (HLO * WLO);
    const int xm = max(c - 1, 0);
    const int xp = min(c + 1, WLO - 1);
    const float* la = lo + ya * WLO;
    const float* lb = lo + yb * WLO;
    const float v0 = la[xm] * gy + lb[xm] * fy;
    const float v1 = la[c]  * gy + lb[c]  * fy;
    const float v2 = la[xp] * gy + lb[xp] * fy;

    // ---- horizontal bilinear: out cols 4c..4c+3 use fx = .625,.875,.125,.375 ----
    const float n0 = (v0 * 0.375f + v1 * 0.625f) * NOISE_SIGMA;
    const float n1 = (v0 * 0.125f + v1 * 0.875f) * NOISE_SIGMA;
    const float n2 = (v1 * 0.875f + v2 * 0.125f) * NOISE_SIGMA;
    const float n3 = (v1 * 0.625f + v2 * 0.375f) * NOISE_SIGMA;

    const size_t idx = (size_t)b * HW + (size_t)t * 4;   // t*4 = y*640 + 4c
    const float4 d  = *reinterpret_cast<const float4*>(depth     + idx);
    const float4 du = *reinterpret_cast<const float4*>(dropout_u + idx);
    const float4 ru = *reinterpret_cast<const float4*>(random_u  + idx);

    // per-component: add noise where depth>0, clip, dropout-zero, random-replace
    float o0 = fminf(fmaxf(d.x + (d.x > 0.0f ? n0 : 0.0f), 0.0f), 1.0f);
    float o1 = fminf(fmaxf(d.y + (d.y > 0.0f ? n1 : 0.0f), 0.0f), 1.0f);
    float o2 = fminf(fmaxf(d.z + (d.z > 0.0f ? n2 : 0.0f), 0.0f), 1.0f);
    float o3 = fminf(fmaxf(d.w + (d.w > 0.0f ? n3 : 0.0f), 0.0f), 1.0f);

    if (du.x < P_DROPOUT) o0 = 0.0f;
    if (du.y < P_DROPOUT) o1 = 0.0f;
    if (du.z < P_DROPOUT) o2 = 0.0f;
    if (du.w < P_DROPOUT) o3 = 0.0f;

    // predicated loads: random_vals cache lines fetched only for hit lanes (~0.3%)
    if (ru.x < P_RANDOM) o0 = random_vals[idx + 0];
    if (ru.y < P_RANDOM) o1 = random_vals[idx + 1];
    if (ru.z < P_RANDOM) o2 = random_vals[idx + 2];
    if (ru.w < P_RANDOM) o3 = random_vals[idx + 3];

    *reinterpret_cast<float4*>(out + idx) = make_float4(o0, o1, o2, o3);
}

// One block (one wave) per batch. Reads the augmented depth at (y,x), then
// fills the <= 18x3 rectangle. Rectangle read happens before any write in
// wave-lockstep; __syncthreads() guards it regardless.
__global__ __launch_bounds__(64) void stick_kernel(
    const float* __restrict__ stick_u,
    const float* __restrict__ horiz_u,
    const float* __restrict__ fallback_vals,
    const int* __restrict__ stick_len,
    const int* __restrict__ stick_width,
    const int* __restrict__ stick_y,
    const int* __restrict__ stick_x,
    float* __restrict__ out)
{
    const int b = blockIdx.x;
    if (!(stick_u[b] < STICK_THRESH)) return;   // stick_on (uniform per block)

    const bool horizontal = horiz_u[b] > 0.5f;
    const int length = stick_len[b] + 1;        // [1,18]
    const int width  = stick_width[b] + 1;      // [1,3]
    const int span_h = horizontal ? width : length;
    const int span_w = horizontal ? length : width;
    const int ymax = max(Hc - span_h, 1) - 1;
    const int xmax = max(Wc - span_w, 1) - 1;
    const int y = min(max(stick_y[b], 0), ymax);
    const int x = min(max(stick_x[b], 0), xmax);

    float* outb = out + (size_t)b * HW;
    const float dval = outb[y * Wc + x];        // post-augmentation sample
    const float val = (dval > 0.0f) ? dval : fallback_vals[b];
    __syncthreads();

    const int total = span_h * span_w;          // <= 54
    for (int i = threadIdx.x; i < total; i += 64) {
        const int rr = i / span_w;
        const int cc = i - rr * span_w;
        outb[(y + rr) * Wc + (x + cc)] = val;
    }
}

extern "C" void kernel_launch(void* const* d_in, const int* in_sizes, int n_in,
                              void* d_out, int out_size, void* d_ws, size_t ws_size,
                              hipStream_t stream) {
    const float* depth       = (const float*)d_in[0];
    const float* noise_lo    = (const float*)d_in[1];
    const float* dropout_u   = (const float*)d_in[2];
    const float* random_u    = (const float*)d_in[3];
    const float* random_vals = (const float*)d_in[4];
    const float* stick_u     = (const float*)d_in[5];
    const float* horiz_u     = (const float*)d_in[6];
    const float* fallback    = (const float*)d_in[7];
    const int*   slen        = (const int*)d_in[8];
    const int*   swid        = (const int*)d_in[9];
    const int*   sy          = (const int*)d_in[10];
    const int*   sx          = (const int*)d_in[11];
    float* out = (float*)d_out;

    dim3 grid(Hc * W4 / 256, Bc);   // 300 x 64 blocks, exact cover
    aug_main_kernel<<<grid, 256, 0, stream>>>(depth, noise_lo, dropout_u,
                                              random_u, random_vals, out);
    stick_kernel<<<Bc, 64, 0, stream>>>(stick_u, horiz_u, fallback,
                                        slen, swid, sy, sx, out);
}

// Round 5
// 285.401 us; speedup vs baseline: 1.0499x; 1.0499x over previous
//
#include <hip/hip_runtime.h>

// DepthAugmentation round 5: round-4 MLP restructure with the nontemporal
// builtin type fixed (clang ext_vector_type instead of HIP float4 struct).
// Round-3 evidence: VGPR=16 => serialized loads; 2.1 TB/s, VALU 10% =>
// latency-bound. Fix: 2 float4 groups per thread (same row), all 6 streaming
// loads issued up-front, nontemporal on single-use streams.

typedef float f32x4 __attribute__((ext_vector_type(4)));

constexpr int Bc  = 64;
constexpr int Hc  = 480;
constexpr int Wc  = 640;
constexpr int HLO = 120;
constexpr int WLO = 160;
constexpr int HW  = Hc * Wc;         // 307200
constexpr int GPB = 80;              // float4 groups per row per column-slot

#define NOISE_SIGMA 0.005f
#define P_DROPOUT   0.003125f
#define P_RANDOM    0.003125f
#define STICK_THRESH 76.8f           // P_STICK * H * W

__global__ __launch_bounds__(256) void aug_main_kernel(
    const float* __restrict__ depth,
    const float* __restrict__ noise_lo,
    const float* __restrict__ dropout_u,
    const float* __restrict__ random_u,
    const float* __restrict__ random_vals,
    float* __restrict__ out)
{
    const int b = blockIdx.y;
    const int t = blockIdx.x * 256 + threadIdx.x;   // [0, 38400): 150 blocks * 256
    const int y = t / GPB;                          // row in [0,480)
    const int c = t - y * GPB;                      // lo-col of group A; group B at c+80

    // ---- vertical bilinear (half-pixel: in_y = y*0.25 - 0.375) ----
    const int r = y & 3, k = y >> 2;
    const int y0 = (r < 2) ? (k - 1) : k;
    const float fy = (r == 0) ? 0.625f : (r == 1) ? 0.875f : (r == 2) ? 0.125f : 0.375f;
    const float gy = 1.0f - fy;
    const int ya = max(y0, 0);
    const int yb = min(y0 + 1, HLO - 1);

    const size_t base = (size_t)b * HW + (size_t)y * Wc;
    const size_t iA = base + (size_t)c * 4;         // group A: cols 4c..4c+3
    const size_t iB = iA + 320;                     // group B: cols 4c+320..4c+323

    // ---- issue ALL streaming loads first (6 outstanding dwordx4 per lane) ----
    const f32x4 dA = __builtin_nontemporal_load(reinterpret_cast<const f32x4*>(depth     + iA));
    const f32x4 dB = __builtin_nontemporal_load(reinterpret_cast<const f32x4*>(depth     + iB));
    const f32x4 uA = __builtin_nontemporal_load(reinterpret_cast<const f32x4*>(dropout_u + iA));
    const f32x4 uB = __builtin_nontemporal_load(reinterpret_cast<const f32x4*>(dropout_u + iB));
    const f32x4 rA = __builtin_nontemporal_load(reinterpret_cast<const f32x4*>(random_u  + iA));
    const f32x4 rB = __builtin_nontemporal_load(reinterpret_cast<const f32x4*>(random_u  + iB));

    // ---- cached noise gathers (75KB/batch footprint -> L1/L2 hits) ----
    const float* lo = noise_lo + (size_t)b * (HLO * WLO);
    const float* la = lo + ya * WLO;
    const float* lb = lo + yb * WLO;
    // group A lo-cols: c-1, c, c+1 (c in [0,79] => c+1 <= 80, no high clamp)
    const int axm = max(c - 1, 0);
    const float a0 = la[axm]  * gy + lb[axm]  * fy;
    const float a1 = la[c]    * gy + lb[c]    * fy;
    const float a2 = la[c+1]  * gy + lb[c+1]  * fy;
    // group B lo-cols: c+79, c+80, c+81 (clamp high at 159)
    const int bxp = min(c + 81, WLO - 1);
    const float b0 = la[c+79] * gy + lb[c+79] * fy;
    const float b1 = la[c+80] * gy + lb[c+80] * fy;
    const float b2 = la[bxp]  * gy + lb[bxp]  * fy;

    // ---- horizontal weights per (col mod 4): taps (lo,hi) = (.375,.625),
    //      (.125,.875), (.875,.125), (.625,.375) ----
    const float nA0 = (a0 * 0.375f + a1 * 0.625f) * NOISE_SIGMA;
    const float nA1 = (a0 * 0.125f + a1 * 0.875f) * NOISE_SIGMA;
    const float nA2 = (a1 * 0.875f + a2 * 0.125f) * NOISE_SIGMA;
    const float nA3 = (a1 * 0.625f + a2 * 0.375f) * NOISE_SIGMA;
    const float nB0 = (b0 * 0.375f + b1 * 0.625f) * NOISE_SIGMA;
    const float nB1 = (b0 * 0.125f + b1 * 0.875f) * NOISE_SIGMA;
    const float nB2 = (b1 * 0.875f + b2 * 0.125f) * NOISE_SIGMA;
    const float nB3 = (b1 * 0.625f + b2 * 0.375f) * NOISE_SIGMA;

    // ---- group A: noise-add (valid only) -> clip -> dropout -> random ----
    float oA0 = fminf(fmaxf(dA.x + (dA.x > 0.0f ? nA0 : 0.0f), 0.0f), 1.0f);
    float oA1 = fminf(fmaxf(dA.y + (dA.y > 0.0f ? nA1 : 0.0f), 0.0f), 1.0f);
    float oA2 = fminf(fmaxf(dA.z + (dA.z > 0.0f ? nA2 : 0.0f), 0.0f), 1.0f);
    float oA3 = fminf(fmaxf(dA.w + (dA.w > 0.0f ? nA3 : 0.0f), 0.0f), 1.0f);
    if (uA.x < P_DROPOUT) oA0 = 0.0f;
    if (uA.y < P_DROPOUT) oA1 = 0.0f;
    if (uA.z < P_DROPOUT) oA2 = 0.0f;
    if (uA.w < P_DROPOUT) oA3 = 0.0f;
    if (rA.x < P_RANDOM) oA0 = random_vals[iA + 0];
    if (rA.y < P_RANDOM) oA1 = random_vals[iA + 1];
    if (rA.z < P_RANDOM) oA2 = random_vals[iA + 2];
    if (rA.w < P_RANDOM) oA3 = random_vals[iA + 3];

    // ---- group B ----
    float oB0 = fminf(fmaxf(dB.x + (dB.x > 0.0f ? nB0 : 0.0f), 0.0f), 1.0f);
    float oB1 = fminf(fmaxf(dB.y + (dB.y > 0.0f ? nB1 : 0.0f), 0.0f), 1.0f);
    float oB2 = fminf(fmaxf(dB.z + (dB.z > 0.0f ? nB2 : 0.0f), 0.0f), 1.0f);
    float oB3 = fminf(fmaxf(dB.w + (dB.w > 0.0f ? nB3 : 0.0f), 0.0f), 1.0f);
    if (uB.x < P_DROPOUT) oB0 = 0.0f;
    if (uB.y < P_DROPOUT) oB1 = 0.0f;
    if (uB.z < P_DROPOUT) oB2 = 0.0f;
    if (uB.w < P_DROPOUT) oB3 = 0.0f;
    if (rB.x < P_RANDOM) oB0 = random_vals[iB + 0];
    if (rB.y < P_RANDOM) oB1 = random_vals[iB + 1];
    if (rB.z < P_RANDOM) oB2 = random_vals[iB + 2];
    if (rB.w < P_RANDOM) oB3 = random_vals[iB + 3];

    f32x4 oA; oA.x = oA0; oA.y = oA1; oA.z = oA2; oA.w = oA3;
    f32x4 oB; oB.x = oB0; oB.y = oB1; oB.z = oB2; oB.w = oB3;
    __builtin_nontemporal_store(oA, reinterpret_cast<f32x4*>(out + iA));
    __builtin_nontemporal_store(oB, reinterpret_cast<f32x4*>(out + iB));
}

// One block (one wave) per batch. Reads the augmented depth at (y,x) (ordered
// after aug_main_kernel by stream), then fills the <= 18x3 rectangle.
__global__ __launch_bounds__(64) void stick_kernel(
    const float* __restrict__ stick_u,
    const float* __restrict__ horiz_u,
    const float* __restrict__ fallback_vals,
    const int* __restrict__ stick_len,
    const int* __restrict__ stick_width,
    const int* __restrict__ stick_y,
    const int* __restrict__ stick_x,
    float* __restrict__ out)
{
    const int b = blockIdx.x;
    if (!(stick_u[b] < STICK_THRESH)) return;   // stick_on (uniform per block)

    const bool horizontal = horiz_u[b] > 0.5f;
    const int length = stick_len[b] + 1;        // [1,18]
    const int width  = stick_width[b] + 1;      // [1,3]
    const int span_h = horizontal ? width : length;
    const int span_w = horizontal ? length : width;
    const int ymax = max(Hc - span_h, 1) - 1;
    const int xmax = max(Wc - span_w, 1) - 1;
    const int y = min(max(stick_y[b], 0), ymax);
    const int x = min(max(stick_x[b], 0), xmax);

    float* outb = out + (size_t)b * HW;
    const float dval = outb[y * Wc + x];        // post-augmentation sample
    const float val = (dval > 0.0f) ? dval : fallback_vals[b];
    __syncthreads();

    const int total = span_h * span_w;          // <= 54
    for (int i = threadIdx.x; i < total; i += 64) {
        const int rr = i / span_w;
        const int cc = i - rr * span_w;
        outb[(y + rr) * Wc + (x + cc)] = val;
    }
}

extern "C" void kernel_launch(void* const* d_in, const int* in_sizes, int n_in,
                              void* d_out, int out_size, void* d_ws, size_t ws_size,
                              hipStream_t stream) {
    const float* depth       = (const float*)d_in[0];
    const float* noise_lo    = (const float*)d_in[1];
    const float* dropout_u   = (const float*)d_in[2];
    const float* random_u    = (const float*)d_in[3];
    const float* random_vals = (const float*)d_in[4];
    const float* stick_u     = (const float*)d_in[5];
    const float* horiz_u     = (const float*)d_in[6];
    const float* fallback    = (const float*)d_in[7];
    const int*   slen        = (const int*)d_in[8];
    const int*   swid        = (const int*)d_in[9];
    const int*   sy          = (const int*)d_in[10];
    const int*   sx          = (const int*)d_in[11];
    float* out = (float*)d_out;

    dim3 grid(Hc * GPB / 256, Bc);   // 150 x 64 blocks, exact cover (38400 thr/batch)
    aug_main_kernel<<<grid, 256, 0, stream>>>(depth, noise_lo, dropout_u,
                                              random_u, random_vals, out);
    stick_kernel<<<Bc, 64, 0, stream>>>(stick_u, horiz_u, fallback,
                                        slen, swid, sy, sx, out);
}

// Round 8
// 279.642 us; speedup vs baseline: 1.0715x; 1.0206x over previous
//
#include <hip/hip_runtime.h>

// DepthAugmentation round 6 (resubmit #2 after broker timeouts):
//  - 4 float4 groups per thread (16 px), stride-40 groups => all 12 streaming
//    loads coalesced and issued up-front (round-5 post-mortem: VGPR=28 could
//    not hold 6 loads in flight; deepen MLP).
//  - stick rectangle folded into the main kernel: aug(y,x) is recomputable
//    from inputs by any thread, so no cross-kernel dependency; saves a launch.

typedef float f32x4 __attribute__((ext_vector_type(4)));

constexpr int Bc  = 64;
constexpr int Hc  = 480;
constexpr int Wc  = 640;
constexpr int HLO = 120;
constexpr int WLO = 160;
constexpr int HW  = Hc * Wc;         // 307200
constexpr int CS  = 40;              // column slots per row (4 groups/thread)

#define NOISE_SIGMA 0.005f
#define P_DROPOUT   0.003125f
#define P_RANDOM    0.003125f
#define STICK_THRESH 76.8f           // P_STICK * H * W

__device__ __forceinline__ float vlerp(const float* la, const float* lb,
                                       int col, float gy, float fy) {
    return la[col] * gy + lb[col] * fy;
}

__global__ __launch_bounds__(256) void aug_main_kernel(
    const float* __restrict__ depth,
    const float* __restrict__ noise_lo,
    const float* __restrict__ dropout_u,
    const float* __restrict__ random_u,
    const float* __restrict__ random_vals,
    const float* __restrict__ stick_u,
    const float* __restrict__ horiz_u,
    const float* __restrict__ fallback_vals,
    const int* __restrict__ stick_len,
    const int* __restrict__ stick_width,
    const int* __restrict__ stick_y,
    const int* __restrict__ stick_x,
    float* __restrict__ out)
{
    const int b = blockIdx.y;
    const int t = blockIdx.x * 256 + threadIdx.x;   // [0,19200): 75 blocks * 256
    const int y = t / CS;                           // row [0,480)
    const int c = t - y * CS;                       // slot [0,40); groups c,c+40,c+80,c+120

    // ---- vertical bilinear (half-pixel: in_y = y*0.25 - 0.375) ----
    const int r = y & 3, k = y >> 2;
    const int y0 = (r < 2) ? (k - 1) : k;
    const float fy = (r == 0) ? 0.625f : (r == 1) ? 0.875f : (r == 2) ? 0.125f : 0.375f;
    const float gy = 1.0f - fy;
    const int ya = max(y0, 0);
    const int yb = min(y0 + 1, HLO - 1);

    const size_t base = (size_t)b * HW + (size_t)y * Wc;
    const size_t iA = base + (size_t)c * 4;
    const size_t iB = iA + 160;
    const size_t iC = iA + 320;
    const size_t iD = iA + 480;

    // ---- issue ALL 12 streaming loads up front ----
    const f32x4 dA = __builtin_nontemporal_load(reinterpret_cast<const f32x4*>(depth     + iA));
    const f32x4 dB = __builtin_nontemporal_load(reinterpret_cast<const f32x4*>(depth     + iB));
    const f32x4 dC = __builtin_nontemporal_load(reinterpret_cast<const f32x4*>(depth     + iC));
    const f32x4 dD = __builtin_nontemporal_load(reinterpret_cast<const f32x4*>(depth     + iD));
    const f32x4 uA = __builtin_nontemporal_load(reinterpret_cast<const f32x4*>(dropout_u + iA));
    const f32x4 uB = __builtin_nontemporal_load(reinterpret_cast<const f32x4*>(dropout_u + iB));
    const f32x4 uC = __builtin_nontemporal_load(reinterpret_cast<const f32x4*>(dropout_u + iC));
    const f32x4 uD = __builtin_nontemporal_load(reinterpret_cast<const f32x4*>(dropout_u + iD));
    const f32x4 rA = __builtin_nontemporal_load(reinterpret_cast<const f32x4*>(random_u  + iA));
    const f32x4 rB = __builtin_nontemporal_load(reinterpret_cast<const f32x4*>(random_u  + iB));
    const f32x4 rC = __builtin_nontemporal_load(reinterpret_cast<const f32x4*>(random_u  + iC));
    const f32x4 rD = __builtin_nontemporal_load(reinterpret_cast<const f32x4*>(random_u  + iD));

    // ---- cached noise taps (L1/L2 hits; 75KB/batch) ----
    const float* lo = noise_lo + (size_t)b * (HLO * WLO);
    const float* la = lo + ya * WLO;
    const float* lb = lo + yb * WLO;
    const float a0 = vlerp(la, lb, max(c - 1, 0), gy, fy);
    const float a1 = vlerp(la, lb, c,             gy, fy);
    const float a2 = vlerp(la, lb, c + 1,         gy, fy);
    const float b0 = vlerp(la, lb, c + 39,        gy, fy);
    const float b1 = vlerp(la, lb, c + 40,        gy, fy);
    const float b2 = vlerp(la, lb, c + 41,        gy, fy);
    const float c0 = vlerp(la, lb, c + 79,        gy, fy);
    const float c1 = vlerp(la, lb, c + 80,        gy, fy);
    const float c2 = vlerp(la, lb, c + 81,        gy, fy);
    const float d0 = vlerp(la, lb, c + 119,       gy, fy);
    const float d1 = vlerp(la, lb, c + 120,       gy, fy);
    const float d2 = vlerp(la, lb, min(c + 121, WLO - 1), gy, fy);

    // horizontal taps per (col mod 4): (lo,hi) weights (.375,.625),(.125,.875),(.875,.125),(.625,.375)
#define HN(p0, p1, p2, n0, n1, n2, n3)                         \
    const float n0 = (p0 * 0.375f + p1 * 0.625f) * NOISE_SIGMA; \
    const float n1 = (p0 * 0.125f + p1 * 0.875f) * NOISE_SIGMA; \
    const float n2 = (p1 * 0.875f + p2 * 0.125f) * NOISE_SIGMA; \
    const float n3 = (p1 * 0.625f + p2 * 0.375f) * NOISE_SIGMA;
    HN(a0, a1, a2, nA0, nA1, nA2, nA3)
    HN(b0, b1, b2, nB0, nB1, nB2, nB3)
    HN(c0, c1, c2, nC0, nC1, nC2, nC3)
    HN(d0, d1, d2, nD0, nD1, nD2, nD3)
#undef HN

    // ---- aug pipeline: noise(valid) -> clip -> dropout -> random ----
#define AUG(dv, uv, rv, n0, n1, n2, n3, idx, q0, q1, q2, q3)                  \
    float q0 = fminf(fmaxf(dv.x + (dv.x > 0.0f ? n0 : 0.0f), 0.0f), 1.0f);    \
    float q1 = fminf(fmaxf(dv.y + (dv.y > 0.0f ? n1 : 0.0f), 0.0f), 1.0f);    \
    float q2 = fminf(fmaxf(dv.z + (dv.z > 0.0f ? n2 : 0.0f), 0.0f), 1.0f);    \
    float q3 = fminf(fmaxf(dv.w + (dv.w > 0.0f ? n3 : 0.0f), 0.0f), 1.0f);    \
    if (uv.x < P_DROPOUT) q0 = 0.0f;                                          \
    if (uv.y < P_DROPOUT) q1 = 0.0f;                                          \
    if (uv.z < P_DROPOUT) q2 = 0.0f;                                          \
    if (uv.w < P_DROPOUT) q3 = 0.0f;                                          \
    if (rv.x < P_RANDOM) q0 = random_vals[idx + 0];                           \
    if (rv.y < P_RANDOM) q1 = random_vals[idx + 1];                           \
    if (rv.z < P_RANDOM) q2 = random_vals[idx + 2];                           \
    if (rv.w < P_RANDOM) q3 = random_vals[idx + 3];
    AUG(dA, uA, rA, nA0, nA1, nA2, nA3, iA, oA0, oA1, oA2, oA3)
    AUG(dB, uB, rB, nB0, nB1, nB2, nB3, iB, oB0, oB1, oB2, oB3)
    AUG(dC, uC, rC, nC0, nC1, nC2, nC3, iC, oC0, oC1, oC2, oC3)
    AUG(dD, uD, rD, nD0, nD1, nD2, nD3, iD, oD0, oD1, oD2, oD3)
#undef AUG

    // ---- stick overwrite (rare: only rows [ry, ry+sh) of each batch) ----
    if (stick_u[b] < STICK_THRESH) {
        const bool horizontal = horiz_u[b] > 0.5f;
        const int length = stick_len[b] + 1;     // [1,18]
        const int width  = stick_width[b] + 1;   // [1,3]
        const int sh = horizontal ? width : length;
        const int sw = horizontal ? length : width;
        const int ry = min(max(stick_y[b], 0), max(Hc - sh, 1) - 1);
        const int rx = min(max(stick_x[b], 0), max(Wc - sw, 1) - 1);
        if (y >= ry && y < ry + sh) {
            // recompute aug(ry, rx) from inputs (identical math to main path)
            const size_t pi = (size_t)b * HW + (size_t)ry * Wc + rx;
            float dv = depth[pi];
            {
                const int vr = ry & 3, vk = ry >> 2;
                const int vy0 = (vr < 2) ? (vk - 1) : vk;
                const float vfy = (vr == 0) ? 0.625f : (vr == 1) ? 0.875f : (vr == 2) ? 0.125f : 0.375f;
                const int vya = max(vy0, 0), vyb = min(vy0 + 1, HLO - 1);
                const int hg = rx >> 2, hr = rx & 3;
                const int hx0 = (hr < 2) ? (hg - 1) : hg;
                const float wfx = (hr == 0) ? 0.625f : (hr == 1) ? 0.875f : (hr == 2) ? 0.125f : 0.375f;
                const int hxa = max(hx0, 0), hxb = min(hx0 + 1, WLO - 1);
                const float nlo = lo[vya * WLO + hxa] * (1.0f - vfy) + lo[vyb * WLO + hxa] * vfy;
                const float nhi = lo[vya * WLO + hxb] * (1.0f - vfy) + lo[vyb * WLO + hxb] * vfy;
                const float nz = (nlo * (1.0f - wfx) + nhi * wfx) * NOISE_SIGMA;
                dv = fminf(fmaxf(dv + (dv > 0.0f ? nz : 0.0f), 0.0f), 1.0f);
            }
            if (dropout_u[pi] < P_DROPOUT) dv = 0.0f;
            if (random_u[pi]  < P_RANDOM)  dv = random_vals[pi];
            const float val = (dv > 0.0f) ? dv : fallback_vals[b];

            const int xlo = rx, xhi = rx + sw;   // [xlo, xhi)
#define APPLY(colbase, q0, q1, q2, q3)                                \
            { const int cb = (colbase);                               \
              if (cb + 0 >= xlo && cb + 0 < xhi) q0 = val;            \
              if (cb + 1 >= xlo && cb + 1 < xhi) q1 = val;            \
              if (cb + 2 >= xlo && cb + 2 < xhi) q2 = val;            \
              if (cb + 3 >= xlo && cb + 3 < xhi) q3 = val; }
            APPLY(c * 4,        oA0, oA1, oA2, oA3)
            APPLY(c * 4 + 160,  oB0, oB1, oB2, oB3)
            APPLY(c * 4 + 320,  oC0, oC1, oC2, oC3)
            APPLY(c * 4 + 480,  oD0, oD1, oD2, oD3)
#undef APPLY
        }
    }

    f32x4 oA; oA.x = oA0; oA.y = oA1; oA.z = oA2; oA.w = oA3;
    f32x4 oB; oB.x = oB0; oB.y = oB1; oB.z = oB2; oB.w = oB3;
    f32x4 oC; oC.x = oC0; oC.y = oC1; oC.z = oC2; oC.w = oC3;
    f32x4 oD; oD.x = oD0; oD.y = oD1; oD.z = oD2; oD.w = oD3;
    __builtin_nontemporal_store(oA, reinterpret_cast<f32x4*>(out + iA));
    __builtin_nontemporal_store(oB, reinterpret_cast<f32x4*>(out + iB));
    __builtin_nontemporal_store(oC, reinterpret_cast<f32x4*>(out + iC));
    __builtin_nontemporal_store(oD, reinterpret_cast<f32x4*>(out + iD));
}

extern "C" void kernel_launch(void* const* d_in, const int* in_sizes, int n_in,
                              void* d_out, int out_size, void* d_ws, size_t ws_size,
                              hipStream_t stream) {
    const float* depth       = (const float*)d_in[0];
    const float* noise_lo    = (const float*)d_in[1];
    const float* dropout_u   = (const float*)d_in[2];
    const float* random_u    = (const float*)d_in[3];
    const float* random_vals = (const float*)d_in[4];
    const float* stick_u     = (const float*)d_in[5];
    const float* horiz_u     = (const float*)d_in[6];
    const float* fallback    = (const float*)d_in[7];
    const int*   slen        = (const int*)d_in[8];
    const int*   swid        = (const int*)d_in[9];
    const int*   sy          = (const int*)d_in[10];
    const int*   sx          = (const int*)d_in[11];
    float* out = (float*)d_out;

    dim3 grid(Hc * CS / 256, Bc);   // 75 x 64 blocks, exact cover (19200 thr/batch)
    aug_main_kernel<<<grid, 256, 0, stream>>>(depth, noise_lo, dropout_u,
                                              random_u, random_vals,
                                              stick_u, horiz_u, fallback,
                                              slen, swid, sy, sx, out);
}